// Round 1
// baseline (337.562 us; speedup 1.0000x reference)
//
#include <hip/hip_runtime.h>

static inline int cdiv(int a, int b) { return (a + b - 1) / b; }

// ---------------- Layer 1: C_in = 1, C_out = 16 ----------------
__global__ __launch_bounds__(256) void conv_l1(
    const float* __restrict__ feats, const int* __restrict__ nmap,
    const float* __restrict__ W, float* __restrict__ out, int N)
{
    __shared__ float4 w4[27 * 4];
    for (int i = threadIdx.x; i < 27 * 4; i += 256)
        w4[i] = reinterpret_cast<const float4*>(W)[i];
    __syncthreads();
    int n = blockIdx.x * 256 + threadIdx.x;
    if (n >= N) return;
    float acc[16];
#pragma unroll
    for (int j = 0; j < 16; ++j) acc[j] = 0.f;
    for (int k = 0; k < 27; ++k) {
        int idx = nmap[(size_t)k * N + n];
        float v = (idx >= 0) ? feats[idx] : 0.f;
#pragma unroll
        for (int cq = 0; cq < 4; ++cq) {
            float4 w = w4[k * 4 + cq];
            acc[cq * 4 + 0] = fmaf(v, w.x, acc[cq * 4 + 0]);
            acc[cq * 4 + 1] = fmaf(v, w.y, acc[cq * 4 + 1]);
            acc[cq * 4 + 2] = fmaf(v, w.z, acc[cq * 4 + 2]);
            acc[cq * 4 + 3] = fmaf(v, w.w, acc[cq * 4 + 3]);
        }
    }
    float4* o = reinterpret_cast<float4*>(out + (size_t)n * 16);
#pragma unroll
    for (int cq = 0; cq < 4; ++cq)
        o[cq] = make_float4(acc[cq * 4 + 0], acc[cq * 4 + 1], acc[cq * 4 + 2], acc[cq * 4 + 3]);
}

// ------------- Generic gathered GEMM for layers 2..5 -------------
// Block: 256 threads, computes TROWS x COUT_T output tile; each thread a 4x4
// register tile. Gathered input rows staged transposed into LDS (padded
// stride), W tile staged into LDS. Optional K-split via blockIdx.z writing
// to partial buffers (deterministic reduction done by reduce_parts).
template<int CIN, int COUT, int COUT_T, int TROWS, int KPER>
__global__ __launch_bounds__(256) void conv_gen(
    const float* __restrict__ x, const int* __restrict__ nmap,
    const float* __restrict__ W, float* __restrict__ out, int N)
{
    constexpr int NTX = COUT_T / 4;
    constexpr int NTY = TROWS / 4;
    static_assert(NTX * NTY == 256, "block mapping must cover tile");
    constexpr int GSTR = TROWS + 4;  // pad to spread LDS banks, keeps 16B align
    __shared__ float gs[CIN][GSTR];      // gathered rows, transposed [ci][row]
    __shared__ float ws[CIN][COUT_T];    // W tile [ci][co]

    const int tid = threadIdx.x;
    const int tx = tid % NTX;
    const int ty = tid / NTX;
    const int row0 = blockIdx.x * TROWS;
    const int co0 = blockIdx.y * COUT_T;
    const int kz = blockIdx.z;

    float acc[4][4];
#pragma unroll
    for (int i = 0; i < 4; ++i)
#pragma unroll
        for (int j = 0; j < 4; ++j) acc[i][j] = 0.f;

    const int kbeg = kz * KPER;
    const int kend = (kbeg + KPER < 27) ? (kbeg + KPER) : 27;

    for (int k = kbeg; k < kend; ++k) {
        __syncthreads();  // protect LDS reuse from previous iteration
        // ---- stage W tile ----
        {
            const float4* Wk4 = reinterpret_cast<const float4*>(W) +
                                (size_t)k * CIN * (COUT / 4);
            constexpr int NW = CIN * COUT_T / 4;
            constexpr int NIT = (NW + 255) / 256;
#pragma unroll
            for (int it = 0; it < NIT; ++it) {
                int i = tid + it * 256;
                if ((NW % 256 == 0) || (i < NW)) {
                    int ci = i / (COUT_T / 4);
                    int coq = i % (COUT_T / 4);
                    float4 v = Wk4[ci * (COUT / 4) + (co0 / 4) + coq];
                    reinterpret_cast<float4*>(&ws[ci][0])[coq] = v;
                }
            }
        }
        // ---- stage gathered rows (transposed) ----
        {
            constexpr int NG = TROWS * CIN / 4;
            constexpr int NIT = (NG + 255) / 256;
#pragma unroll
            for (int it = 0; it < NIT; ++it) {
                int i = tid + it * 256;
                if ((NG % 256 == 0) || (i < NG)) {
                    int r = i / (CIN / 4);
                    int cq = i % (CIN / 4);
                    int row = row0 + r;
                    int idx = (row < N) ? nmap[(size_t)k * N + row] : -1;
                    float4 v = make_float4(0.f, 0.f, 0.f, 0.f);
                    if (idx >= 0)
                        v = reinterpret_cast<const float4*>(x + (size_t)idx * CIN)[cq];
                    gs[cq * 4 + 0][r] = v.x;
                    gs[cq * 4 + 1][r] = v.y;
                    gs[cq * 4 + 2][r] = v.z;
                    gs[cq * 4 + 3][r] = v.w;
                }
            }
        }
        __syncthreads();
        // ---- compute: outer products over ci ----
#pragma unroll 16
        for (int ci = 0; ci < CIN; ++ci) {
            float4 wv = *reinterpret_cast<const float4*>(&ws[ci][tx * 4]);
            float4 gv = *reinterpret_cast<const float4*>(&gs[ci][ty * 4]);
            float gg[4] = {gv.x, gv.y, gv.z, gv.w};
            float ww[4] = {wv.x, wv.y, wv.z, wv.w};
#pragma unroll
            for (int i = 0; i < 4; ++i)
#pragma unroll
                for (int j = 0; j < 4; ++j)
                    acc[i][j] = fmaf(gg[i], ww[j], acc[i][j]);
        }
    }

    float* op = out + (size_t)kz * ((size_t)N * COUT);
#pragma unroll
    for (int i = 0; i < 4; ++i) {
        int r = row0 + ty * 4 + i;
        if (r < N) {
            float4 v = make_float4(acc[i][0], acc[i][1], acc[i][2], acc[i][3]);
            *reinterpret_cast<float4*>(op + (size_t)r * COUT + co0 + tx * 4) = v;
        }
    }
}

// ------------- deterministic fixed-order K-split reduction -------------
__global__ __launch_bounds__(256) void reduce_parts(
    const float* __restrict__ p, float* __restrict__ out, int m4, int S)
{
    int i = blockIdx.x * 256 + threadIdx.x;
    if (i >= m4) return;
    const float4* p4 = reinterpret_cast<const float4*>(p);
    float4 a = p4[i];
    for (int s = 1; s < S; ++s) {
        float4 v = p4[(size_t)s * m4 + i];
        a.x += v.x; a.y += v.y; a.z += v.z; a.w += v.w;
    }
    reinterpret_cast<float4*>(out)[i] = a;
}

extern "C" void kernel_launch(void* const* d_in, const int* in_sizes, int n_in,
                              void* d_out, int out_size, void* d_ws, size_t ws_size,
                              hipStream_t stream)
{
    // setup_inputs() dict order: feats, W1, nmap1, W2, nmap2, ..., W5, nmap5
    const float* feats = (const float*)d_in[0];
    const float* W1 = (const float*)d_in[1];
    const int*   nm1 = (const int*)d_in[2];
    const float* W2 = (const float*)d_in[3];
    const int*   nm2 = (const int*)d_in[4];
    const float* W3 = (const float*)d_in[5];
    const int*   nm3 = (const int*)d_in[6];
    const float* W4 = (const float*)d_in[7];
    const int*   nm4 = (const int*)d_in[8];
    const float* W5 = (const float*)d_in[9];
    const int*   nm5 = (const int*)d_in[10];

    const int N1 = in_sizes[2] / 27;
    const int N2 = in_sizes[4] / 27;
    const int N3 = in_sizes[6] / 27;
    const int N4 = in_sizes[8] / 27;
    const int N5 = in_sizes[10] / 27;

    float* x1 = (float*)d_ws;
    float* x2 = x1 + (size_t)N1 * 16;
    float* x3 = x2 + (size_t)N2 * 32;
    float* x4 = x3 + (size_t)N3 * 64;
    float* p4 = x4 + (size_t)N4 * 128;           // 3 partials of N4*128
    float* p5 = p4 + (size_t)3 * N4 * 128;       // 9 partials of N5*512
    float* outf = (float*)d_out;

    // L1: 1 -> 16
    conv_l1<<<cdiv(N1, 256), 256, 0, stream>>>(feats, nm1, W1, x1, N1);
    // L2: 16 -> 32   (tile 128 rows x 32 cols)
    conv_gen<16, 32, 32, 128, 27>
        <<<dim3(cdiv(N2, 128), 1, 1), 256, 0, stream>>>(x1, nm2, W2, x2, N2);
    // L3: 32 -> 64   (tile 64 x 64)
    conv_gen<32, 64, 64, 64, 27>
        <<<dim3(cdiv(N3, 64), 1, 1), 256, 0, stream>>>(x2, nm3, W3, x3, N3);
    // L4: 64 -> 128  (tile 64 x 64, K split 3-way)
    conv_gen<64, 128, 64, 64, 9>
        <<<dim3(cdiv(N4, 64), 2, 3), 256, 0, stream>>>(x3, nm4, W4, p4, N4);
    reduce_parts<<<cdiv(N4 * 128 / 4, 256), 256, 0, stream>>>(p4, x4, N4 * 128 / 4, 3);
    // L5: 128 -> 512 (tile 64 x 64, K split 9-way)
    conv_gen<128, 512, 64, 64, 3>
        <<<dim3(cdiv(N5, 64), 8, 9), 256, 0, stream>>>(x4, nm5, W5, p5, N5);
    reduce_parts<<<cdiv(N5 * 512 / 4, 256), 256, 0, stream>>>(p5, outf, N5 * 512 / 4, 9);
}

// Round 2
// 259.544 us; speedup vs baseline: 1.3006x; 1.3006x over previous
//
#include <hip/hip_runtime.h>

typedef unsigned short u16;
typedef unsigned int u32;
typedef __attribute__((ext_vector_type(8))) short short8;
typedef __attribute__((ext_vector_type(4))) float float4v;

static inline int cdiv(int a, int b) { return (a + b - 1) / b; }

__device__ __forceinline__ u16 f2bf(float f) {
    u32 u = __float_as_uint(f);
    u = (u + 0x7fffu + ((u >> 16) & 1u)) >> 16;
    return (u16)u;
}
__device__ __forceinline__ float bf2f(u16 s) {
    return __uint_as_float(((u32)s) << 16);
}

// W (K=27*CIN rows, COUT cols) fp32 -> transposed bf16 hi/lo (COUT, K)
__global__ __launch_bounds__(256) void wsplit(
    const float* __restrict__ W, u16* __restrict__ th, u16* __restrict__ tl,
    int K, int COUT)
{
    int e = blockIdx.x * 256 + threadIdx.x;
    if (e >= K * COUT) return;
    int kk = e / COUT, co = e % COUT;
    float w = W[e];
    u16 h = f2bf(w);
    u16 l = f2bf(w - bf2f(h));
    th[(size_t)co * K + kk] = h;
    tl[(size_t)co * K + kk] = l;
}

// ---------------- Layer 1: C_in = 1, C_out = 16, bf16-pair output ------------
__global__ __launch_bounds__(256) void conv_l1(
    const float* __restrict__ feats, const int* __restrict__ nmap,
    const float* __restrict__ W, u16* __restrict__ oh, u16* __restrict__ ol, int N)
{
    __shared__ float4 w4[27 * 4];
    for (int i = threadIdx.x; i < 27 * 4; i += 256)
        w4[i] = reinterpret_cast<const float4*>(W)[i];
    __syncthreads();
    int n = blockIdx.x * 256 + threadIdx.x;
    if (n >= N) return;
    float acc[16];
#pragma unroll
    for (int j = 0; j < 16; ++j) acc[j] = 0.f;
    for (int k = 0; k < 27; ++k) {
        int idx = nmap[(size_t)k * N + n];
        float v = (idx >= 0) ? feats[idx] : 0.f;
#pragma unroll
        for (int cq = 0; cq < 4; ++cq) {
            float4 w = w4[k * 4 + cq];
            acc[cq * 4 + 0] = fmaf(v, w.x, acc[cq * 4 + 0]);
            acc[cq * 4 + 1] = fmaf(v, w.y, acc[cq * 4 + 1]);
            acc[cq * 4 + 2] = fmaf(v, w.z, acc[cq * 4 + 2]);
            acc[cq * 4 + 3] = fmaf(v, w.w, acc[cq * 4 + 3]);
        }
    }
    u32 hu[8], lu[8];
#pragma unroll
    for (int q = 0; q < 8; ++q) {
        u16 h0 = f2bf(acc[2 * q]), h1 = f2bf(acc[2 * q + 1]);
        u16 l0 = f2bf(acc[2 * q] - bf2f(h0)), l1 = f2bf(acc[2 * q + 1] - bf2f(h1));
        hu[q] = (u32)h0 | ((u32)h1 << 16);
        lu[q] = (u32)l0 | ((u32)l1 << 16);
    }
    uint4* po = reinterpret_cast<uint4*>(oh + (size_t)n * 16);
    po[0] = make_uint4(hu[0], hu[1], hu[2], hu[3]);
    po[1] = make_uint4(hu[4], hu[5], hu[6], hu[7]);
    uint4* pl = reinterpret_cast<uint4*>(ol + (size_t)n * 16);
    pl[0] = make_uint4(lu[0], lu[1], lu[2], lu[3]);
    pl[1] = make_uint4(lu[4], lu[5], lu[6], lu[7]);
}

// ------------- MFMA gathered GEMM, 3-term bf16 hi/lo split -------------------
// A[n][kk] = x[nmap[kk/CIN][n]][kk%CIN] (hi/lo), B = Wt[co][kk] (hi/lo).
// Block: 256 threads = 4 waves, tile BM x BN, wave tile WM x WN of 16x16 frags.
template<int CIN, int COUT, int BM, int BN, int WM, int WN, int KSPLIT, bool BFOUT>
__global__ __launch_bounds__(256) void conv_mfma(
    const u16* __restrict__ xh, const u16* __restrict__ xl,
    const int* __restrict__ nmap,
    const u16* __restrict__ wth, const u16* __restrict__ wtl,
    float* __restrict__ outf, u16* __restrict__ oh, u16* __restrict__ ol,
    int N)
{
    constexpr int K = 27 * CIN;
    constexpr int KSTEPS = (K + 31) / 32;
    static_assert(KSTEPS % KSPLIT == 0, "ksplit must divide ksteps");
    constexpr int KPER = KSTEPS / KSPLIT;
    constexpr int WAVES_M = BM / WM, WAVES_N = BN / WN;
    static_assert(WAVES_M * WAVES_N == 4, "4 waves");
    constexpr int FM = WM / 16, FN = WN / 16;
    constexpr int AST = 40;  // padded row stride (u16): 80B -> 2-way banks (free)

    __shared__ __align__(16) u16 Ah[BM * AST];
    __shared__ __align__(16) u16 Al[BM * AST];
    __shared__ __align__(16) u16 Bh[BN * AST];
    __shared__ __align__(16) u16 Bl[BN * AST];

    const int tid = threadIdx.x;
    const int row0 = blockIdx.x * BM;
    const int co0 = blockIdx.y * BN;
    const int kz = blockIdx.z;

    const int lane = tid & 63;
    const int wave = tid >> 6;
    const int wm = wave / WAVES_N;
    const int wn = wave % WAVES_N;
    const int fr = lane & 15;
    const int kc = (lane >> 4) * 8;

    float4v acc[FM][FN];
#pragma unroll
    for (int i = 0; i < FM; ++i)
#pragma unroll
        for (int j = 0; j < FN; ++j) acc[i][j] = (float4v){0.f, 0.f, 0.f, 0.f};

    const int ksbeg = kz * KPER;

    for (int s = 0; s < KPER; ++s) {
        const int ks = ksbeg + s;
        __syncthreads();
        // ---- stage A (gather) ----
        constexpr int AT = BM * 4;
        constexpr int AIT = (AT + 255) / 256;
#pragma unroll
        for (int it = 0; it < AIT; ++it) {
            int t = tid + it * 256;
            if ((AT % 256 == 0) || (t < AT)) {
                int r = t >> 2, c = t & 3;
                int kk = ks * 32 + c * 8;
                int row = row0 + r;
                int idx = -1;
                if (row < N && kk < K) idx = nmap[(size_t)(kk / CIN) * N + row];
                uint4 vh = make_uint4(0, 0, 0, 0), vl = make_uint4(0, 0, 0, 0);
                if (idx >= 0) {
                    size_t base = (size_t)idx * CIN + (kk % CIN);
                    vh = *reinterpret_cast<const uint4*>(xh + base);
                    vl = *reinterpret_cast<const uint4*>(xl + base);
                }
                *reinterpret_cast<uint4*>(&Ah[r * AST + c * 8]) = vh;
                *reinterpret_cast<uint4*>(&Al[r * AST + c * 8]) = vl;
            }
        }
        // ---- stage B (dense W, pre-transposed) ----
        constexpr int BT = BN * 4;
        constexpr int BIT = (BT + 255) / 256;
#pragma unroll
        for (int it = 0; it < BIT; ++it) {
            int t = tid + it * 256;
            if ((BT % 256 == 0) || (t < BT)) {
                int r = t >> 2, c = t & 3;
                int kk = ks * 32 + c * 8;
                uint4 vh = make_uint4(0, 0, 0, 0), vl = make_uint4(0, 0, 0, 0);
                if (kk < K) {
                    size_t base = (size_t)(co0 + r) * K + kk;
                    vh = *reinterpret_cast<const uint4*>(wth + base);
                    vl = *reinterpret_cast<const uint4*>(wtl + base);
                }
                *reinterpret_cast<uint4*>(&Bh[r * AST + c * 8]) = vh;
                *reinterpret_cast<uint4*>(&Bl[r * AST + c * 8]) = vl;
            }
        }
        __syncthreads();
        // ---- fragments + MFMA ----
        short8 avh[FM], avl[FM], bvh[FN], bvl[FN];
#pragma unroll
        for (int i = 0; i < FM; ++i) {
            int r = wm * WM + i * 16 + fr;
            avh[i] = *reinterpret_cast<const short8*>(&Ah[r * AST + kc]);
            avl[i] = *reinterpret_cast<const short8*>(&Al[r * AST + kc]);
        }
#pragma unroll
        for (int j = 0; j < FN; ++j) {
            int r = wn * WN + j * 16 + fr;
            bvh[j] = *reinterpret_cast<const short8*>(&Bh[r * AST + kc]);
            bvl[j] = *reinterpret_cast<const short8*>(&Bl[r * AST + kc]);
        }
#pragma unroll
        for (int i = 0; i < FM; ++i)
#pragma unroll
            for (int j = 0; j < FN; ++j) {
                acc[i][j] = __builtin_amdgcn_mfma_f32_16x16x32_bf16(avh[i], bvh[j], acc[i][j], 0, 0, 0);
                acc[i][j] = __builtin_amdgcn_mfma_f32_16x16x32_bf16(avh[i], bvl[j], acc[i][j], 0, 0, 0);
                acc[i][j] = __builtin_amdgcn_mfma_f32_16x16x32_bf16(avl[i], bvh[j], acc[i][j], 0, 0, 0);
            }
    }

    // ---- epilogue: D row=(lane>>4)*4+reg, col=lane&15 (m89) ----
    const int orow0 = row0 + wm * WM + (lane >> 4) * 4;
    const int ocol0 = co0 + wn * WN + fr;
#pragma unroll
    for (int i = 0; i < FM; ++i)
#pragma unroll
        for (int j = 0; j < FN; ++j)
#pragma unroll
            for (int q = 0; q < 4; ++q) {
                int r = orow0 + i * 16 + q;
                int c = ocol0 + j * 16;
                if (r < N) {
                    float v = acc[i][j][q];
                    if constexpr (BFOUT) {
                        u16 h = f2bf(v);
                        oh[(size_t)r * COUT + c] = h;
                        ol[(size_t)r * COUT + c] = f2bf(v - bf2f(h));
                    } else {
                        outf[(size_t)kz * N * COUT + (size_t)r * COUT + c] = v;
                    }
                }
            }
}

// ------------- deterministic fixed-order K-split reductions ------------------
__global__ __launch_bounds__(256) void reduce_f32(
    const float* __restrict__ p, float* __restrict__ out, int m, int S)
{
    int i = blockIdx.x * 256 + threadIdx.x;
    if (i >= m) return;
    float a = p[i];
    for (int s = 1; s < S; ++s) a += p[(size_t)s * m + i];
    out[i] = a;
}
__global__ __launch_bounds__(256) void reduce_bf(
    const float* __restrict__ p, u16* __restrict__ oh, u16* __restrict__ ol,
    int m, int S)
{
    int i = blockIdx.x * 256 + threadIdx.x;
    if (i >= m) return;
    float a = p[i];
    for (int s = 1; s < S; ++s) a += p[(size_t)s * m + i];
    u16 h = f2bf(a);
    oh[i] = h;
    ol[i] = f2bf(a - bf2f(h));
}

extern "C" void kernel_launch(void* const* d_in, const int* in_sizes, int n_in,
                              void* d_out, int out_size, void* d_ws, size_t ws_size,
                              hipStream_t stream)
{
    const float* feats = (const float*)d_in[0];
    const float* W1 = (const float*)d_in[1];
    const int*   nm1 = (const int*)d_in[2];
    const float* W2 = (const float*)d_in[3];
    const int*   nm2 = (const int*)d_in[4];
    const float* W3 = (const float*)d_in[5];
    const int*   nm3 = (const int*)d_in[6];
    const float* W4 = (const float*)d_in[7];
    const int*   nm4 = (const int*)d_in[8];
    const float* W5 = (const float*)d_in[9];
    const int*   nm5 = (const int*)d_in[10];

    const int M1 = in_sizes[2] / 27;
    const int M2 = in_sizes[4] / 27;
    const int M3 = in_sizes[6] / 27;
    const int M4 = in_sizes[8] / 27;
    const int M5 = in_sizes[10] / 27;

    u16* x1h = (u16*)d_ws;
    u16* x1l = x1h + (size_t)M1 * 16;
    u16* x2h = x1l + (size_t)M1 * 16;
    u16* x2l = x2h + (size_t)M2 * 32;
    u16* x3h = x2l + (size_t)M2 * 32;
    u16* x3l = x3h + (size_t)M3 * 64;
    u16* x4h = x3l + (size_t)M3 * 64;
    u16* x4l = x4h + (size_t)M4 * 128;
    u16* wt2h = x4l + (size_t)M4 * 128;
    u16* wt2l = wt2h + 432 * 32;
    u16* wt3h = wt2l + 432 * 32;
    u16* wt3l = wt3h + 864 * 64;
    u16* wt4h = wt3l + 864 * 64;
    u16* wt4l = wt4h + 1728 * 128;
    u16* wt5h = wt4l + 1728 * 128;
    u16* wt5l = wt5h + (size_t)3456 * 512;
    u16* uend = wt5l + (size_t)3456 * 512;
    float* p4 = (float*)(((uintptr_t)uend + 15) & ~(uintptr_t)15);
    float* p5 = p4 + (size_t)2 * M4 * 128;

    wsplit<<<cdiv(432 * 32, 256), 256, 0, stream>>>(W2, wt2h, wt2l, 432, 32);
    wsplit<<<cdiv(864 * 64, 256), 256, 0, stream>>>(W3, wt3h, wt3l, 864, 64);
    wsplit<<<cdiv(1728 * 128, 256), 256, 0, stream>>>(W4, wt4h, wt4l, 1728, 128);
    wsplit<<<cdiv(3456 * 512, 256), 256, 0, stream>>>(W5, wt5h, wt5l, 3456, 512);

    conv_l1<<<cdiv(M1, 256), 256, 0, stream>>>(feats, nm1, W1, x1h, x1l, M1);

    // L2: 16 -> 32
    conv_mfma<16, 32, 128, 32, 32, 32, 1, true>
        <<<dim3(cdiv(M2, 128), 1, 1), 256, 0, stream>>>(
            x1h, x1l, nm2, wt2h, wt2l, nullptr, x2h, x2l, M2);
    // L3: 32 -> 64
    conv_mfma<32, 64, 64, 64, 32, 32, 1, true>
        <<<dim3(cdiv(M3, 64), 1, 1), 256, 0, stream>>>(
            x2h, x2l, nm3, wt3h, wt3l, nullptr, x3h, x3l, M3);
    // L4: 64 -> 128, K-split 2
    conv_mfma<64, 128, 64, 64, 32, 32, 2, false>
        <<<dim3(cdiv(M4, 64), 2, 2), 256, 0, stream>>>(
            x3h, x3l, nm4, wt4h, wt4l, p4, nullptr, nullptr, M4);
    reduce_bf<<<cdiv(M4 * 128, 256), 256, 0, stream>>>(p4, x4h, x4l, M4 * 128, 2);
    // L5: 128 -> 512, K-split 2
    conv_mfma<128, 512, 32, 64, 16, 32, 2, false>
        <<<dim3(cdiv(M5, 32), 8, 2), 256, 0, stream>>>(
            x4h, x4l, nm5, wt5h, wt5l, p5, nullptr, nullptr, M5);
    reduce_f32<<<cdiv(M5 * 512, 256), 256, 0, stream>>>(p5, (float*)d_out, M5 * 512, 2);
}

// Round 3
// 224.555 us; speedup vs baseline: 1.5032x; 1.1558x over previous
//
#include <hip/hip_runtime.h>

typedef unsigned short u16;
typedef unsigned int u32;
typedef __attribute__((ext_vector_type(8))) short short8;
typedef __attribute__((ext_vector_type(4))) float float4v;

static inline int cdiv(int a, int b) { return (a + b - 1) / b; }

__device__ __forceinline__ u16 f2bf(float f) {
    u32 u = __float_as_uint(f);
    u = (u + 0x7fffu + ((u >> 16) & 1u)) >> 16;
    return (u16)u;
}
__device__ __forceinline__ float bf2f(u16 s) {
    return __uint_as_float(((u32)s) << 16);
}

// W (K rows, COUT cols) fp32 -> transposed bf16 hi/lo (COUT, K)
__global__ __launch_bounds__(256) void wsplit(
    const float* __restrict__ W, u16* __restrict__ th, u16* __restrict__ tl,
    int K, int COUT)
{
    int e = blockIdx.x * 256 + threadIdx.x;
    if (e >= K * COUT) return;
    int kk = e / COUT, co = e % COUT;
    float w = W[e];
    u16 h = f2bf(w);
    u16 l = f2bf(w - bf2f(h));
    th[(size_t)co * K + kk] = h;
    tl[(size_t)co * K + kk] = l;
}

// ------ Layer 1: C_in=1 -> 16, k-split x4 in-block for gather MLP ------
__global__ __launch_bounds__(256) void conv_l1(
    const float* __restrict__ feats, const int* __restrict__ nmap,
    const float* __restrict__ W, u16* __restrict__ oh, u16* __restrict__ ol, int N)
{
    __shared__ float4 w4[27 * 4];
    __shared__ float part[4][64][17];  // +1 pad: conflict-free
    for (int i = threadIdx.x; i < 27 * 4; i += 256)
        w4[i] = reinterpret_cast<const float4*>(W)[i];
    __syncthreads();

    const int tx = threadIdx.x & 63;   // row in block
    const int tz = threadIdx.x >> 6;   // k-part 0..3 (7,7,7,6 offsets)
    const int row = blockIdx.x * 64 + tx;

    float acc[16];
#pragma unroll
    for (int j = 0; j < 16; ++j) acc[j] = 0.f;

#pragma unroll
    for (int s = 0; s < 7; ++s) {
        int k = tz * 7 + s;
        if (k < 27) {
            int idx = (row < N) ? nmap[(size_t)k * N + row] : -1;
            float v = (idx >= 0) ? feats[idx] : 0.f;
#pragma unroll
            for (int cq = 0; cq < 4; ++cq) {
                float4 w = w4[k * 4 + cq];
                acc[cq * 4 + 0] = fmaf(v, w.x, acc[cq * 4 + 0]);
                acc[cq * 4 + 1] = fmaf(v, w.y, acc[cq * 4 + 1]);
                acc[cq * 4 + 2] = fmaf(v, w.z, acc[cq * 4 + 2]);
                acc[cq * 4 + 3] = fmaf(v, w.w, acc[cq * 4 + 3]);
            }
        }
    }
#pragma unroll
    for (int c = 0; c < 16; ++c) part[tz][tx][c] = acc[c];
    __syncthreads();

    // reduce in fixed order; each thread: 1 row x 4 channels
    const int r = threadIdx.x & 63;
    const int cs = (threadIdx.x >> 6) * 4;
    const int orow = blockIdx.x * 64 + r;
    if (orow >= N) return;
    float o[4];
#pragma unroll
    for (int j = 0; j < 4; ++j) {
        float a = part[0][r][cs + j];
#pragma unroll
        for (int p = 1; p < 4; ++p) a += part[p][r][cs + j];
        o[j] = a;
    }
    u32 h01 = (u32)f2bf(o[0]) | ((u32)f2bf(o[1]) << 16);
    u32 h23 = (u32)f2bf(o[2]) | ((u32)f2bf(o[3]) << 16);
    float l0 = o[0] - bf2f(f2bf(o[0])), l1 = o[1] - bf2f(f2bf(o[1]));
    float l2 = o[2] - bf2f(f2bf(o[2])), l3 = o[3] - bf2f(f2bf(o[3]));
    u32 g01 = (u32)f2bf(l0) | ((u32)f2bf(l1) << 16);
    u32 g23 = (u32)f2bf(l2) | ((u32)f2bf(l3) << 16);
    *reinterpret_cast<uint2*>(oh + (size_t)orow * 16 + cs) = make_uint2(h01, h23);
    *reinterpret_cast<uint2*>(ol + (size_t)orow * 16 + cs) = make_uint2(g01, g23);
}

// ------ Direct-fragment MFMA gathered GEMM (no LDS, no barriers) ------
// A[n][kk] = x[nmap[kk/CIN][n]][kk%CIN] (hi/lo), B = Wt[co][kk] (hi/lo).
template<int CIN, int COUT, int BM, int BN, int WAVES_M, int WAVES_N,
         int WM, int WN, int KSPLIT, bool BFOUT>
__global__ __launch_bounds__(256) void conv_direct(
    const u16* __restrict__ xh, const u16* __restrict__ xl,
    const int* __restrict__ nmap,
    const u16* __restrict__ wth, const u16* __restrict__ wtl,
    float* __restrict__ outf, u16* __restrict__ oh, u16* __restrict__ ol,
    int N)
{
    constexpr int K = 27 * CIN;
    constexpr int KSTEPS = (K + 31) / 32;
    static_assert(KSTEPS % KSPLIT == 0, "ksplit divides ksteps");
    constexpr int KPER = KSTEPS / KSPLIT;
    static_assert(WAVES_M * WAVES_N == 4 && WAVES_M * WM == BM && WAVES_N * WN == BN, "");
    constexpr int FM = WM / 16, FN = WN / 16;

    const int lane = threadIdx.x & 63;
    const int wave = threadIdx.x >> 6;
    const int wm = wave / WAVES_N, wn = wave % WAVES_N;
    const int fr = lane & 15;
    const int kc = (lane >> 4) * 8;
    const int row0 = blockIdx.x * BM + wm * WM;
    const int co0 = blockIdx.y * BN + wn * WN;
    const int kz = blockIdx.z;

    float4v acc[FM][FN];
#pragma unroll
    for (int i = 0; i < FM; ++i)
#pragma unroll
        for (int j = 0; j < FN; ++j) acc[i][j] = (float4v){0.f, 0.f, 0.f, 0.f};

    for (int s = 0; s < KPER; ++s) {
        const int ks = kz * KPER + s;
        const int kk = ks * 32 + kc;
        const bool kok = (kk < K);

        short8 avh[FM], avl[FM], bvh[FN], bvl[FN];
#pragma unroll
        for (int i = 0; i < FM; ++i) {
            int r = row0 + i * 16 + fr;
            int idx = (kok && r < N) ? nmap[(size_t)(kk / CIN) * N + r] : -1;
            if (idx >= 0) {
                size_t base = (size_t)idx * CIN + (kk & (CIN - 1));
                avh[i] = *reinterpret_cast<const short8*>(xh + base);
                avl[i] = *reinterpret_cast<const short8*>(xl + base);
            } else {
                avh[i] = (short8){0, 0, 0, 0, 0, 0, 0, 0};
                avl[i] = (short8){0, 0, 0, 0, 0, 0, 0, 0};
            }
        }
#pragma unroll
        for (int j = 0; j < FN; ++j) {
            int co = co0 + j * 16 + fr;
            if (kok) {
                size_t base = (size_t)co * K + kk;
                bvh[j] = *reinterpret_cast<const short8*>(wth + base);
                bvl[j] = *reinterpret_cast<const short8*>(wtl + base);
            } else {
                bvh[j] = (short8){0, 0, 0, 0, 0, 0, 0, 0};
                bvl[j] = (short8){0, 0, 0, 0, 0, 0, 0, 0};
            }
        }
#pragma unroll
        for (int i = 0; i < FM; ++i)
#pragma unroll
            for (int j = 0; j < FN; ++j) {
                acc[i][j] = __builtin_amdgcn_mfma_f32_16x16x32_bf16(avh[i], bvh[j], acc[i][j], 0, 0, 0);
                acc[i][j] = __builtin_amdgcn_mfma_f32_16x16x32_bf16(avh[i], bvl[j], acc[i][j], 0, 0, 0);
                acc[i][j] = __builtin_amdgcn_mfma_f32_16x16x32_bf16(avl[i], bvh[j], acc[i][j], 0, 0, 0);
            }
    }

    // D layout: row=(lane>>4)*4+q, col=lane&15 (m89)
    const int orow0 = row0 + (lane >> 4) * 4;
    const int ocol0 = co0 + fr;
#pragma unroll
    for (int i = 0; i < FM; ++i)
#pragma unroll
        for (int j = 0; j < FN; ++j)
#pragma unroll
            for (int q = 0; q < 4; ++q) {
                int r = orow0 + i * 16 + q;
                int c = ocol0 + j * 16;
                if (r < N) {
                    float v = acc[i][j][q];
                    if constexpr (BFOUT) {
                        u16 h = f2bf(v);
                        oh[(size_t)r * COUT + c] = h;
                        ol[(size_t)r * COUT + c] = f2bf(v - bf2f(h));
                    } else {
                        outf[(size_t)kz * N * COUT + (size_t)r * COUT + c] = v;
                    }
                }
            }
}

// ------ deterministic fixed-order K-split reductions (float4) ------
__global__ __launch_bounds__(256) void reduce_f32(
    const float* __restrict__ p, float* __restrict__ out, int m4, int S)
{
    int i = blockIdx.x * 256 + threadIdx.x;
    if (i >= m4) return;
    const float4* p4 = reinterpret_cast<const float4*>(p);
    float4 a = p4[i];
    for (int s = 1; s < S; ++s) {
        float4 v = p4[(size_t)s * m4 + i];
        a.x += v.x; a.y += v.y; a.z += v.z; a.w += v.w;
    }
    reinterpret_cast<float4*>(out)[i] = a;
}
__global__ __launch_bounds__(256) void reduce_bf(
    const float* __restrict__ p, u16* __restrict__ oh, u16* __restrict__ ol,
    int m, int S)
{
    int i = blockIdx.x * 256 + threadIdx.x;
    if (i >= m) return;
    float a = p[i];
    for (int s = 1; s < S; ++s) a += p[(size_t)s * m + i];
    u16 h = f2bf(a);
    oh[i] = h;
    ol[i] = f2bf(a - bf2f(h));
}

extern "C" void kernel_launch(void* const* d_in, const int* in_sizes, int n_in,
                              void* d_out, int out_size, void* d_ws, size_t ws_size,
                              hipStream_t stream)
{
    const float* feats = (const float*)d_in[0];
    const float* W1 = (const float*)d_in[1];
    const int*   nm1 = (const int*)d_in[2];
    const float* W2 = (const float*)d_in[3];
    const int*   nm2 = (const int*)d_in[4];
    const float* W3 = (const float*)d_in[5];
    const int*   nm3 = (const int*)d_in[6];
    const float* W4 = (const float*)d_in[7];
    const int*   nm4 = (const int*)d_in[8];
    const float* W5 = (const float*)d_in[9];
    const int*   nm5 = (const int*)d_in[10];

    const int M1 = in_sizes[2] / 27;
    const int M2 = in_sizes[4] / 27;
    const int M3 = in_sizes[6] / 27;
    const int M4 = in_sizes[8] / 27;
    const int M5 = in_sizes[10] / 27;

    u16* x1h = (u16*)d_ws;
    u16* x1l = x1h + (size_t)M1 * 16;
    u16* x2h = x1l + (size_t)M1 * 16;
    u16* x2l = x2h + (size_t)M2 * 32;
    u16* x3h = x2l + (size_t)M2 * 32;
    u16* x3l = x3h + (size_t)M3 * 64;
    u16* x4h = x3l + (size_t)M3 * 64;
    u16* x4l = x4h + (size_t)M4 * 128;
    u16* wt2h = x4l + (size_t)M4 * 128;
    u16* wt2l = wt2h + 432 * 32;
    u16* wt3h = wt2l + 432 * 32;
    u16* wt3l = wt3h + 864 * 64;
    u16* wt4h = wt3l + 864 * 64;
    u16* wt4l = wt4h + 1728 * 128;
    u16* wt5h = wt4l + 1728 * 128;
    u16* wt5l = wt5h + (size_t)3456 * 512;
    u16* uend = wt5l + (size_t)3456 * 512;
    float* p4 = (float*)(((uintptr_t)uend + 15) & ~(uintptr_t)15);
    float* p5 = p4 + (size_t)6 * M4 * 128;

    wsplit<<<cdiv(432 * 32, 256), 256, 0, stream>>>(W2, wt2h, wt2l, 432, 32);
    wsplit<<<cdiv(864 * 64, 256), 256, 0, stream>>>(W3, wt3h, wt3l, 864, 64);
    wsplit<<<cdiv(1728 * 128, 256), 256, 0, stream>>>(W4, wt4h, wt4l, 1728, 128);
    wsplit<<<cdiv(3456 * 512, 256), 256, 0, stream>>>(W5, wt5h, wt5l, 3456, 512);

    conv_l1<<<cdiv(M1, 64), 256, 0, stream>>>(feats, nm1, W1, x1h, x1l, M1);

    // L2: 16 -> 32, block 256x32, waves 4x1 of 64x32
    conv_direct<16, 32, 256, 32, 4, 1, 64, 32, 1, true>
        <<<dim3(cdiv(M2, 256), 1, 1), 256, 0, stream>>>(
            x1h, x1l, nm2, wt2h, wt2l, nullptr, x2h, x2l, M2);
    // L3: 32 -> 64, block 128x64, waves 2x2 of 64x32
    conv_direct<32, 64, 128, 64, 2, 2, 64, 32, 1, true>
        <<<dim3(cdiv(M3, 128), 1, 1), 256, 0, stream>>>(
            x2h, x2l, nm3, wt3h, wt3l, nullptr, x3h, x3l, M3);
    // L4: 64 -> 128, block 64x128, waves 1x4 of 64x32, K-split 6
    conv_direct<64, 128, 64, 128, 1, 4, 64, 32, 6, false>
        <<<dim3(cdiv(M4, 64), 1, 6), 256, 0, stream>>>(
            x3h, x3l, nm4, wt4h, wt4l, p4, nullptr, nullptr, M4);
    reduce_bf<<<cdiv(M4 * 128, 256), 256, 0, stream>>>(p4, x4h, x4l, M4 * 128, 6);
    // L5: 128 -> 512, block 32x128, waves 1x4 of 32x32, K-split 6
    conv_direct<128, 512, 32, 128, 1, 4, 32, 32, 6, false>
        <<<dim3(cdiv(M5, 32), 4, 6), 256, 0, stream>>>(
            x4h, x4l, nm5, wt5h, wt5l, p5, nullptr, nullptr, M5);
    reduce_f32<<<cdiv(M5 * 512 / 4, 256), 256, 0, stream>>>(p5, (float*)d_out, M5 * 512 / 4, 6);
}